// Round 4
// baseline (3488.653 us; speedup 1.0000x reference)
//
#include <hip/hip_runtime.h>
#include <hip/hip_bf16.h>

#define VOCAB 5000
#define HIDDEN 1024
#define SEQ 128
#define BATCH 64
#define L1NB 16   // layer-1 blocks, 64 cols each
#define L2NB 32   // layer-2 blocks, 32 cols each
#define NBLK (L1NB + L2NB)
#define RING 8    // y1 ring slots
#define NGRID 240 // 48 rnn + 192 proj stealers; 1 block/CU (136K LDS), 16-CU slack
#define NTILE (128 * 20)  // proj tiles: 128 row-tiles x 20 col-tiles
#define LDS_BYTES 139264

typedef __hip_bfloat16 bf16;
typedef short bf16x8 __attribute__((ext_vector_type(8)));   // 8 bf16 = 4 VGPRs (MFMA A/B frag)
typedef float f32x4 __attribute__((ext_vector_type(4)));    // MFMA C/D frag

__device__ __forceinline__ float b2f(bf16 v) { return __bfloat162float(v); }

// ---------------------------------------------------------------------------
// Dtype self-detection: low 16-bit halves of fp32 weights decode as bf16 with
// exp>=127 ~50% of the time; real bf16 weights (|w|<=0.03) never do.
// ---------------------------------------------------------------------------
__device__ __forceinline__ bool detect_fp32(const void* w) {
    const unsigned* p = (const unsigned*)w;
    unsigned big = 0;
    #pragma unroll
    for (int i = 0; i < 64; ++i) {
        unsigned e = (p[i] >> 7) & 0xFFu;
        big |= (e >= 127u) ? 1u : 0u;
    }
    return big != 0;
}

__global__ __launch_bounds__(256) void convert_w(const void* __restrict__ src,
                                                 bf16* __restrict__ dst, int n,
                                                 const void* __restrict__ det) {
    const bool f32 = detect_fp32(det);
    int i = (blockIdx.x * 256 + threadIdx.x) * 4;
    if (f32) {
        const float* s = (const float*)src;
        #pragma unroll
        for (int j = 0; j < 4; ++j) if (i + j < n) dst[i + j] = __float2bfloat16(s[i + j]);
    } else {
        const bf16* s = (const bf16*)src;
        #pragma unroll
        for (int j = 0; j < 4; ++j) if (i + j < n) dst[i + j] = s[i + j];
    }
}

__global__ __launch_bounds__(256) void make_bias(const void* __restrict__ a,
                                                 const void* __restrict__ b,
                                                 float* __restrict__ dst, int n,
                                                 const void* __restrict__ det) {
    const bool f32 = detect_fp32(det);
    int i = blockIdx.x * 256 + threadIdx.x;
    if (i >= n) return;
    float v = f32 ? ((const float*)a)[i] : b2f(((const bf16*)a)[i]);
    if (b)  v += f32 ? ((const float*)b)[i] : b2f(((const bf16*)b)[i]);
    dst[i] = v;
}

// ---------------------------------------------------------------------------
// MALL-coherent (system-scope) 16B load/store: bypass L1+L2, hit the die-level
// coherence point directly. Removes the need for per-step acquire fences
// (buffer_inv) and keeps rnn blocks' L2 CLEAN so release wbl2 is ~free.
// Loads are issued async; caller batches then calls vm_drain() (waitcnt +
// sched_barrier per guide rule 18) before use.
// ---------------------------------------------------------------------------
__device__ __forceinline__ void ld_sys_b128(bf16x8* dst, const void* p) {
    asm volatile("global_load_dwordx4 %0, %1, off sc0 sc1" : "=v"(*dst) : "v"(p));
}
__device__ __forceinline__ void st_sys_b128(void* p, bf16x8 v) {
    asm volatile("global_store_dwordx4 %0, %1, off sc0 sc1" :: "v"(p), "v"(v) : "memory");
}
__device__ __forceinline__ void vm_drain() {
    asm volatile("s_waitcnt vmcnt(0)" ::: "memory");
    __builtin_amdgcn_sched_barrier(0);
}

// Relaxed-only poll (agent-scope loads execute at the coherence point; no
// acquire fence / buffer_inv needed). BOUNDED: a broken protocol surfaces as
// an absmax failure with a profile, never a GPU hang that kills the container.
// SLP is a template param: __builtin_amdgcn_s_sleep requires a constant (R3).
template <int SLP>
__device__ __forceinline__ void wait_flag(int* flag, int target, long maxit) {
    long n = 0;
    while (__hip_atomic_load(flag, __ATOMIC_RELAXED, __HIP_MEMORY_SCOPE_AGENT) < target) {
        __builtin_amdgcn_s_sleep(SLP);
        if (++n > maxit) return;   // ~1-2 s guard at the call-site cadence
    }
}

// ---------------------------------------------------------------------------
// Fused persistent kernel (NORMAL launch — cooperative launch is not graph-
// capturable and was silently dropped in R1; 240 blocks x 136K LDS = 1/CU
// with 16-CU slack, so all blocks are co-resident; rnn blocks dispatch first):
//   blocks  0..15 : layer-1 recurrence, 64 hidden cols each
//   blocks 16..47 : layer-2 recurrence, 32 hidden cols each (K=2048 fused)
//   blocks 48..239: projection tiles (work-stealing), gated on f2[bm]
// rnn blocks fall through into the projection pool when their 128 steps end.
// All cross-block data (y1 ring, y2) moves via sc0sc1 write-through stores /
// read-through loads; flags relaxed-poll + release-add. y2 rows are
// write-once-then-immutable and never pre-cached, so proj may read them with
// normal cached loads after f2[bm].
// ---------------------------------------------------------------------------
__global__ __launch_bounds__(256, 1) void rnn_fused(
    const int*  __restrict__ x,        // (S,B) int32
    const void* __restrict__ Wih1raw,  // (H,V) fp32 or bf16 (gather + detect)
    const bf16* __restrict__ whh1,     // (H,H) ws bf16
    const bf16* __restrict__ wih2,     // (H,H) ws bf16
    const bf16* __restrict__ whh2,     // (H,H) ws bf16
    const float* __restrict__ bias1,   // (H)
    const float* __restrict__ bias2,   // (H)
    bf16* __restrict__ y1r,            // (RING,B,H) layer-1 ring
    bf16* __restrict__ y2,             // (S,B,H) layer-2 history
    int* __restrict__ f1,              // (SEQ) flags
    int* __restrict__ f2,              // (SEQ) flags
    int* __restrict__ pt,              // proj tile counter
    const bf16* __restrict__ wfcb,     // (V,H) ws bf16
    const float* __restrict__ bfcf,    // (V)
    void* __restrict__ outp)
{
    extern __shared__ bf16 lds[];      // 139264 B (128K weights + 8K cbuf)
    const int bid  = blockIdx.x;
    const int tid  = threadIdx.x;
    const int wave = tid >> 6;
    const int lane = tid & 63;
    const int q    = lane >> 4;
    const int l15  = lane & 15;
    const size_t BH = (size_t)BATCH * HIDDEN;
    const int  mrow  = wave * 16 + l15;          // batch row for A frag

    if (bid < L1NB) {
        // ================= layer 1: 64 cols =================
        const bool f32in = detect_fp32(Wih1raw);
        const int n0 = bid * 64;
        // stage whh1 slice: 64 rows x 128 chunks (16B), swizzle c ^ (row&7)
        for (int idx = tid; idx < 64 * 128; idx += 256) {
            const int row = idx >> 7, c = idx & 127;
            *(bf16x8*)&lds[(size_t)((row << 7) + (c ^ (row & 7))) * 8] =
                *(const bf16x8*)(whh1 + (size_t)(n0 + row) * HIDDEN + c * 8);
        }
        __syncthreads();

        float breg[4];
        #pragma unroll
        for (int t = 0; t < 4; ++t) breg[t] = bias1[n0 + t * 16 + l15];
        bf16* cb = lds + 65536;   // 8 KB transpose stage (byte offset 128K)

        for (int s = 0; s < SEQ; ++s) {
            // ---- embedding gather: cached (no per-step L2 inv -> stays
            // L2-hot); issued before the wait so latency hides under it.
            float xg[4][4];
            {
                int xv[4];
                #pragma unroll
                for (int r = 0; r < 4; ++r) xv[r] = x[s * BATCH + wave * 16 + q * 4 + r];
                #pragma unroll
                for (int t = 0; t < 4; ++t)
                    #pragma unroll
                    for (int r = 0; r < 4; ++r) {
                        const size_t gi = (size_t)(n0 + t * 16 + l15) * VOCAB + xv[r];
                        xg[t][r] = f32in ? ((const float*)Wih1raw)[gi]
                                         : b2f(((const bf16*)Wih1raw)[gi]);
                    }
            }
            if (tid == 0) {
                if (s >= 1)    wait_flag<1>(&f1[s - 1], L1NB, 40000000L);
                if (s >= RING) wait_flag<1>(&f2[s - RING], L2NB, 40000000L);
            }
            __syncthreads();

            f32x4 acc[4];
            #pragma unroll
            for (int t = 0; t < 4; ++t) acc[t] = (f32x4){0.f,0.f,0.f,0.f};
            if (s > 0) {
                const bf16* arow = y1r + (size_t)((s - 1) & (RING - 1)) * BH
                                       + (size_t)mrow * HIDDEN + q * 8;
                bf16x8 af[32];
                #pragma unroll
                for (int k = 0; k < 32; ++k) ld_sys_b128(&af[k], arow + k * 32);
                vm_drain();
                #pragma unroll
                for (int k = 0; k < 32; ++k) {
                    const int chb = k * 4 + q;
                    #pragma unroll
                    for (int t = 0; t < 4; ++t) {
                        const int row = t * 16 + l15;
                        bf16x8 bw = *(const bf16x8*)&lds[(size_t)((row << 7) + (chb ^ (row & 7))) * 8];
                        acc[t] = __builtin_amdgcn_mfma_f32_16x16x32_bf16(af[k], bw, acc[t], 0, 0, 0);
                    }
                }
            }
            // epilogue: tanh -> LDS transpose stage -> coalesced 16B sc0sc1 stores
            #pragma unroll
            for (int t = 0; t < 4; ++t)
                #pragma unroll
                for (int r = 0; r < 4; ++r) {
                    const int b = wave * 16 + q * 4 + r;
                    cb[b * 64 + t * 16 + l15] =
                        __float2bfloat16(tanhf(acc[t][r] + breg[t] + xg[t][r]));
                }
            __syncthreads();
            bf16* outb = y1r + (size_t)(s & (RING - 1)) * BH;
            #pragma unroll
            for (int it = 0; it < 2; ++it) {
                const int c = it * 256 + tid;          // 0..511
                const int row = c >> 3, off = (c & 7) * 8;
                st_sys_b128(outb + (size_t)row * HIDDEN + n0 + off,
                            *(const bf16x8*)&cb[row * 64 + off]);
            }
            vm_drain();        // stores acked at MALL before the flag
            __syncthreads();
            if (tid == 0)
                __hip_atomic_fetch_add(&f1[s], 1, __ATOMIC_RELEASE, __HIP_MEMORY_SCOPE_AGENT);
        }
    } else if (bid < NBLK) {
        // ================= layer 2: 32 cols, K=2048 =================
        const int n0 = (bid - L1NB) * 32;
        // stage [wih2|whh2] slice: 32 rows x 256 chunks
        for (int idx = tid; idx < 32 * 256; idx += 256) {
            const int row = idx >> 8, c = idx & 255;
            const bf16* W = (c < 128) ? wih2 : whh2;
            *(bf16x8*)&lds[(size_t)((row << 8) + (c ^ (row & 7))) * 8] =
                *(const bf16x8*)(W + (size_t)(n0 + row) * HIDDEN + (c & 127) * 8);
        }
        __syncthreads();

        float breg[2];
        #pragma unroll
        for (int t = 0; t < 2; ++t) breg[t] = bias2[n0 + t * 16 + l15];
        bf16* cb = lds + 65536;   // 4 KB transpose stage

        for (int st = 0; st < SEQ; ++st) {
            if (tid == 0) {
                wait_flag<1>(&f1[st], L1NB, 40000000L);
                if (st >= 1) wait_flag<1>(&f2[st - 1], L2NB, 40000000L);
            }
            __syncthreads();

            f32x4 acc[2];
            #pragma unroll
            for (int t = 0; t < 2; ++t) acc[t] = (f32x4){0.f,0.f,0.f,0.f};

            // pass 0: input contribution y1[st] (chunks 0..127)
            {
                const bf16* arow = y1r + (size_t)(st & (RING - 1)) * BH
                                       + (size_t)mrow * HIDDEN + q * 8;
                bf16x8 af[32];
                #pragma unroll
                for (int k = 0; k < 32; ++k) ld_sys_b128(&af[k], arow + k * 32);
                vm_drain();
                #pragma unroll
                for (int k = 0; k < 32; ++k) {
                    const int chb = k * 4 + q;
                    #pragma unroll
                    for (int t = 0; t < 2; ++t) {
                        const int row = t * 16 + l15;
                        bf16x8 bw = *(const bf16x8*)&lds[(size_t)((row << 8) + (chb ^ (row & 7))) * 8];
                        acc[t] = __builtin_amdgcn_mfma_f32_16x16x32_bf16(af[k], bw, acc[t], 0, 0, 0);
                    }
                }
            }
            // pass 1: recurrent contribution y2[st-1] (chunks 128..255)
            if (st > 0) {
                const bf16* arow = y2 + (size_t)(st - 1) * BH
                                      + (size_t)mrow * HIDDEN + q * 8;
                bf16x8 af[32];
                #pragma unroll
                for (int k = 0; k < 32; ++k) ld_sys_b128(&af[k], arow + k * 32);
                vm_drain();
                #pragma unroll
                for (int k = 0; k < 32; ++k) {
                    const int chb = 128 + k * 4 + q;
                    #pragma unroll
                    for (int t = 0; t < 2; ++t) {
                        const int row = t * 16 + l15;
                        bf16x8 bw = *(const bf16x8*)&lds[(size_t)((row << 8) + (chb ^ (row & 7))) * 8];
                        acc[t] = __builtin_amdgcn_mfma_f32_16x16x32_bf16(af[k], bw, acc[t], 0, 0, 0);
                    }
                }
            }
            #pragma unroll
            for (int t = 0; t < 2; ++t)
                #pragma unroll
                for (int r = 0; r < 4; ++r) {
                    const int b = wave * 16 + q * 4 + r;
                    cb[b * 32 + t * 16 + l15] =
                        __float2bfloat16(tanhf(acc[t][r] + breg[t]));
                }
            __syncthreads();
            {
                bf16* outb = y2 + (size_t)st * BH;
                const int row = tid >> 2, off = (tid & 3) * 8;
                st_sys_b128(outb + (size_t)row * HIDDEN + n0 + off,
                            *(const bf16x8*)&cb[row * 32 + off]);
            }
            vm_drain();
            __syncthreads();
            if (tid == 0)
                __hip_atomic_fetch_add(&f2[st], 1, __ATOMIC_RELEASE, __HIP_MEMORY_SCOPE_AGENT);
        }
    }

    // ================= projection: work-stealing tile pool =================
    // ans = y2 @ W_fc^T + b_fc -> (8192 x 5000). Tile = 64M x 256N, 4 waves
    // of 32x128. Tiles ordered bm-major so eligibility follows step order.
    // rnn blocks join after their recurrence (tail acceleration).
    {
        const bool f32out = detect_fp32(Wih1raw);
        __shared__ int stile;
        bf16* cb = lds;                          // 32 KB C staging
        const int wm = wave & 1, wn = wave >> 1;
        const bf16x8 zf = (bf16x8){0,0,0,0,0,0,0,0};

        for (;;) {
            if (tid == 0)
                stile = __hip_atomic_fetch_add(pt, 1, __ATOMIC_RELAXED, __HIP_MEMORY_SCOPE_AGENT);
            __syncthreads();                     // broadcast + cbuf reuse fence
            const int tile = stile;
            if (tile >= NTILE) break;
            const int bm = tile / 20, bn = tile % 20;
            // coarse backoff: ~192 pollers share f2 lines; keep MALL pressure low
            if (tid == 0) wait_flag<16>(&f2[bm], L2NB, 2500000L);
            __syncthreads();

            const int m0 = bm * 64 + wm * 32;
            const int n0 = bn * 256 + wn * 128;

            f32x4 acc[2][8];
            #pragma unroll
            for (int i = 0; i < 2; ++i)
                #pragma unroll
                for (int t = 0; t < 8; ++t) acc[i][t] = (f32x4){0.f,0.f,0.f,0.f};

            const bf16* a0p = y2 + (size_t)(m0 + l15) * HIDDEN + q * 8;
            const bf16* a1p = a0p + (size_t)16 * HIDDEN;

            for (int k0 = 0; k0 < HIDDEN; k0 += 32) {
                bf16x8 af0 = *(const bf16x8*)(a0p + k0);
                bf16x8 af1 = *(const bf16x8*)(a1p + k0);
                #pragma unroll
                for (int t = 0; t < 8; ++t) {
                    const int n = n0 + t * 16 + l15;
                    bf16x8 bw = (n < VOCAB)
                        ? *(const bf16x8*)(wfcb + (size_t)n * HIDDEN + k0 + q * 8) : zf;
                    acc[0][t] = __builtin_amdgcn_mfma_f32_16x16x32_bf16(af0, bw, acc[0][t], 0, 0, 0);
                    acc[1][t] = __builtin_amdgcn_mfma_f32_16x16x32_bf16(af1, bw, acc[1][t], 0, 0, 0);
                }
            }

            if (f32out) {
                #pragma unroll
                for (int t = 0; t < 8; ++t) {
                    const int col = n0 + t * 16 + l15;
                    if (col >= VOCAB) continue;
                    const float bias = bfcf[col];
                    #pragma unroll
                    for (int i = 0; i < 2; ++i)
                        #pragma unroll
                        for (int r = 0; r < 4; ++r) {
                            const int row = m0 + i * 16 + q * 4 + r;
                            ((float*)outp)[(size_t)row * VOCAB + col] = acc[i][t][r] + bias;
                        }
                }
                continue;
            }

            // bf16 path: stage in LDS, store coalesced 16B/lane full lines.
            #pragma unroll
            for (int t = 0; t < 8; ++t) {
                const int col  = n0 + t * 16 + l15;
                const int cloc = wn * 128 + t * 16 + l15;
                const float bias = (col < VOCAB) ? bfcf[col] : 0.f;
                #pragma unroll
                for (int i = 0; i < 2; ++i)
                    #pragma unroll
                    for (int r = 0; r < 4; ++r) {
                        const int rloc = wm * 32 + i * 16 + q * 4 + r;
                        cb[rloc * 256 + cloc] = __float2bfloat16(acc[i][t][r] + bias);
                    }
            }
            __syncthreads();
            bf16* ob = (bf16*)outp;
            for (int cidx = tid; cidx < 64 * 32; cidx += 256) {
                const int row = cidx >> 5;
                const int c8  = (cidx & 31) * 8;
                const int gcol = bn * 256 + c8;      // VOCAB % 8 == 0: chunk all-in/out
                if (gcol < VOCAB)
                    *(bf16x8*)(ob + (size_t)(bm * 64 + row) * VOCAB + gcol) =
                        *(const bf16x8*)&cb[row * 256 + c8];
            }
            // cbuf-reuse fence is the top-of-loop __syncthreads
        }
    }
}

__global__ __launch_bounds__(256) void state_copy(
    const bf16* __restrict__ y1r, const bf16* __restrict__ y2,
    void* __restrict__ outp, const void* __restrict__ det)
{
    const bool f32out = detect_fp32(det);
    const int t = blockIdx.x * blockDim.x + threadIdx.x;
    const int BH = BATCH * HIDDEN;
    const size_t ofs = (size_t)SEQ * BATCH * VOCAB;
    float v;
    if (t < BH) v = b2f(y1r[(size_t)((SEQ - 1) & (RING - 1)) * BH + t]);
    else        v = b2f(y2[(size_t)(SEQ - 1) * BH + (t - BH)]);
    if (f32out) ((float*)outp)[ofs + t] = v;
    else        ((bf16*)outp)[ofs + t] = __float2bfloat16(v);
}

extern "C" void kernel_launch(void* const* d_in, const int* in_sizes, int n_in,
                              void* d_out, int out_size, void* d_ws, size_t ws_size,
                              hipStream_t stream) {
    const int*  x       = (const int*)d_in[0];
    const void* Wih1raw = d_in[1];
    const void* Whh1raw = d_in[2];
    const void* bih1    = d_in[3];
    const void* bhh1    = d_in[4];
    const void* Wih2raw = d_in[5];
    const void* Whh2raw = d_in[6];
    const void* bih2    = d_in[7];
    const void* bhh2    = d_in[8];
    const void* Wfcraw  = d_in[9];
    const void* bfcraw  = d_in[10];

    // ws layout: flags (1 KB), bf16 arrays, fp32 biases, tile counter (~34.2 MB)
    char* wsb = (char*)d_ws;
    int*   f1    = (int*)wsb;                                    // SEQ ints
    int*   f2    = f1 + SEQ;                                     // SEQ ints
    bf16*  y2    = (bf16*)(wsb + 1024);
    bf16*  y1r   = y2   + (size_t)SEQ * BATCH * HIDDEN;          // RING*B*H
    bf16*  whh1  = y1r  + (size_t)RING * BATCH * HIDDEN;
    bf16*  wih2  = whh1 + (size_t)HIDDEN * HIDDEN;
    bf16*  whh2  = wih2 + (size_t)HIDDEN * HIDDEN;
    bf16*  wfcb  = whh2 + (size_t)HIDDEN * HIDDEN;
    float* bias1 = (float*)(wfcb + (size_t)VOCAB * HIDDEN);
    float* bias2 = bias1 + HIDDEN;
    float* bfcf  = bias2 + HIDDEN;
    int*   pt    = (int*)(bfcf + VOCAB);                         // proj tile counter

    // Allow >128K dynamic LDS (host-side attribute; graph-capture-safe).
    static bool lds_ok = false;
    if (!lds_ok) {
        (void)hipFuncSetAttribute((const void*)rnn_fused,
                                  hipFuncAttributeMaxDynamicSharedMemorySize, LDS_BYTES);
        lds_ok = true;
    }

    (void)hipMemsetAsync(f1, 0, 2 * SEQ * sizeof(int), stream);
    (void)hipMemsetAsync(pt, 0, sizeof(int), stream);

    const int HH = HIDDEN * HIDDEN, VH = VOCAB * HIDDEN;
    convert_w<<<(HH + 1023) / 1024, 256, 0, stream>>>(Whh1raw, whh1, HH, Wih1raw);
    convert_w<<<(HH + 1023) / 1024, 256, 0, stream>>>(Wih2raw, wih2, HH, Wih1raw);
    convert_w<<<(HH + 1023) / 1024, 256, 0, stream>>>(Whh2raw, whh2, HH, Wih1raw);
    convert_w<<<(VH + 1023) / 1024, 256, 0, stream>>>(Wfcraw,  wfcb, VH, Wih1raw);
    make_bias<<<(HIDDEN + 255) / 256, 256, 0, stream>>>(bih1, bhh1, bias1, HIDDEN, Wih1raw);
    make_bias<<<(HIDDEN + 255) / 256, 256, 0, stream>>>(bih2, bhh2, bias2, HIDDEN, Wih1raw);
    make_bias<<<(VOCAB + 255) / 256, 256, 0, stream>>>(bfcraw, nullptr, bfcf, VOCAB, Wih1raw);

    // NORMAL launch (cooperative launch is not graph-capturable -> R1 no-op).
    // 240 blocks x 136K LDS = 1 block/CU, 16-CU slack: all co-resident, and
    // rnn blocks (bid<48) dispatch first so the flag protocol cannot starve.
    rnn_fused<<<NGRID, 256, LDS_BYTES, stream>>>(x, Wih1raw, whh1, wih2, whh2,
                                                 bias1, bias2, y1r, y2, f1, f2,
                                                 pt, wfcb, bfcf, d_out);

    state_copy<<<(2 * BATCH * HIDDEN) / 256, 256, 0, stream>>>(y1r, y2, d_out, Wih1raw);
}

// Round 5
// 2243.253 us; speedup vs baseline: 1.5552x; 1.5552x over previous
//
#include <hip/hip_runtime.h>
#include <hip/hip_bf16.h>

#define VOCAB 5000
#define HIDDEN 1024
#define SEQ 128
#define BATCH 64
#define L1NB 16   // layer-1 blocks, 64 cols each
#define L2NB 32   // layer-2 blocks, 32 cols each
#define NBLK (L1NB + L2NB)
#define RING 8    // y1 ring slots
#define LDS_BYTES 139264

typedef __hip_bfloat16 bf16;
typedef short bf16x8 __attribute__((ext_vector_type(8)));   // 8 bf16 = 4 VGPRs (MFMA A/B frag)
typedef float f32x4 __attribute__((ext_vector_type(4)));    // MFMA C/D frag

__device__ __forceinline__ float b2f(bf16 v) { return __bfloat162float(v); }

// ---------------------------------------------------------------------------
// Dtype self-detection: low 16-bit halves of fp32 weights decode as bf16 with
// exp>=127 ~50% of the time; real bf16 weights (|w|<=0.03) never do.
// ---------------------------------------------------------------------------
__device__ __forceinline__ bool detect_fp32(const void* w) {
    const unsigned* p = (const unsigned*)w;
    unsigned big = 0;
    #pragma unroll
    for (int i = 0; i < 64; ++i) {
        unsigned e = (p[i] >> 7) & 0xFFu;
        big |= (e >= 127u) ? 1u : 0u;
    }
    return big != 0;
}

__global__ __launch_bounds__(256) void convert_w(const void* __restrict__ src,
                                                 bf16* __restrict__ dst, int n,
                                                 const void* __restrict__ det) {
    const bool f32 = detect_fp32(det);
    int i = (blockIdx.x * 256 + threadIdx.x) * 4;
    if (f32) {
        const float* s = (const float*)src;
        #pragma unroll
        for (int j = 0; j < 4; ++j) if (i + j < n) dst[i + j] = __float2bfloat16(s[i + j]);
    } else {
        const bf16* s = (const bf16*)src;
        #pragma unroll
        for (int j = 0; j < 4; ++j) if (i + j < n) dst[i + j] = s[i + j];
    }
}

__global__ __launch_bounds__(256) void make_bias(const void* __restrict__ a,
                                                 const void* __restrict__ b,
                                                 float* __restrict__ dst, int n,
                                                 const void* __restrict__ det) {
    const bool f32 = detect_fp32(det);
    int i = blockIdx.x * 256 + threadIdx.x;
    if (i >= n) return;
    float v = f32 ? ((const float*)a)[i] : b2f(((const bf16*)a)[i]);
    if (b)  v += f32 ? ((const float*)b)[i] : b2f(((const bf16*)b)[i]);
    dst[i] = v;
}

// ---------------------------------------------------------------------------
// MALL-coherent (system-scope) 16B load/store: bypass L1+L2, hit the die-level
// coherence point directly. Removes the need for per-step acquire fences
// (buffer_inv) and keeps rnn blocks' L2 CLEAN so release wbl2 is ~free.
// Protocol PROVEN CORRECT in R4 (passed, absmax 9.8e-4).
// ---------------------------------------------------------------------------
__device__ __forceinline__ void ld_sys_b128(bf16x8* dst, const void* p) {
    asm volatile("global_load_dwordx4 %0, %1, off sc0 sc1" : "=v"(*dst) : "v"(p));
}
__device__ __forceinline__ void st_sys_b128(void* p, bf16x8 v) {
    asm volatile("global_store_dwordx4 %0, %1, off sc0 sc1" :: "v"(p), "v"(v) : "memory");
}
__device__ __forceinline__ void vm_drain() {
    asm volatile("s_waitcnt vmcnt(0)" ::: "memory");
    __builtin_amdgcn_sched_barrier(0);
}

// Relaxed-only poll (agent-scope loads execute at the coherence point; no
// acquire fence / buffer_inv needed). BOUNDED so a broken protocol surfaces
// as an absmax failure with a profile, never a container-killing hang.
template <int SLP>
__device__ __forceinline__ void wait_flag(int* flag, int target, long maxit) {
    long n = 0;
    while (__hip_atomic_load(flag, __ATOMIC_RELAXED, __HIP_MEMORY_SCOPE_AGENT) < target) {
        __builtin_amdgcn_s_sleep(SLP);
        if (++n > maxit) return;   // ~1-2 s guard
    }
}

// ---------------------------------------------------------------------------
// Decoupled recurrence ONLY (48 blocks). R4 lesson: fusing the latency-
// critical flag/RTT chain with proj's ~1 GB MALL streaming inflated every
// round-trip in the chain (13.4 -> ~26 us/step). Proj is a separate dispatch.
//   blocks  0..15 : layer-1, 64 hidden cols each
//   blocks 16..47 : layer-2, 32 hidden cols each (K=2048 fused)
// f1/f2 waits polled CONCURRENTLY by tid 0 / tid 64 (were sequential in R4).
// ---------------------------------------------------------------------------
__global__ __launch_bounds__(256, 1) void rnn_persistent(
    const int*  __restrict__ x,        // (S,B) int32
    const void* __restrict__ Wih1raw,  // (H,V) fp32 or bf16 (gather + detect)
    const bf16* __restrict__ whh1,     // (H,H) ws bf16
    const bf16* __restrict__ wih2,     // (H,H) ws bf16
    const bf16* __restrict__ whh2,     // (H,H) ws bf16
    const float* __restrict__ bias1,   // (H)
    const float* __restrict__ bias2,   // (H)
    bf16* __restrict__ y1r,            // (RING,B,H) layer-1 ring
    bf16* __restrict__ y2,             // (S,B,H) layer-2 history
    int* __restrict__ f1,              // (SEQ) flags
    int* __restrict__ f2)              // (SEQ) flags
{
    extern __shared__ bf16 lds[];      // 139264 B (128K weights + 8K cbuf)
    const int bid  = blockIdx.x;
    const int tid  = threadIdx.x;
    const int wave = tid >> 6;
    const int lane = tid & 63;
    const int q    = lane >> 4;
    const int l15  = lane & 15;
    const size_t BH = (size_t)BATCH * HIDDEN;
    const int  mrow  = wave * 16 + l15;          // batch row for A frag

    if (bid < L1NB) {
        // ================= layer 1: 64 cols =================
        const bool f32in = detect_fp32(Wih1raw);
        const int n0 = bid * 64;
        // stage whh1 slice: 64 rows x 128 chunks (16B), swizzle c ^ (row&7)
        for (int idx = tid; idx < 64 * 128; idx += 256) {
            const int row = idx >> 7, c = idx & 127;
            *(bf16x8*)&lds[(size_t)((row << 7) + (c ^ (row & 7))) * 8] =
                *(const bf16x8*)(whh1 + (size_t)(n0 + row) * HIDDEN + c * 8);
        }
        __syncthreads();

        float breg[4];
        #pragma unroll
        for (int t = 0; t < 4; ++t) breg[t] = bias1[n0 + t * 16 + l15];
        bf16* cb = lds + 65536;   // 8 KB transpose stage (byte offset 128K)

        for (int s = 0; s < SEQ; ++s) {
            // ---- embedding gather: cached (no per-step L2 inv; with only 48
            // blocks on the machine the 1.3 MB/block slice stays L2-hot).
            float xg[4][4];
            {
                int xv[4];
                #pragma unroll
                for (int r = 0; r < 4; ++r) xv[r] = x[s * BATCH + wave * 16 + q * 4 + r];
                #pragma unroll
                for (int t = 0; t < 4; ++t)
                    #pragma unroll
                    for (int r = 0; r < 4; ++r) {
                        const size_t gi = (size_t)(n0 + t * 16 + l15) * VOCAB + xv[r];
                        xg[t][r] = f32in ? ((const float*)Wih1raw)[gi]
                                         : b2f(((const bf16*)Wih1raw)[gi]);
                    }
            }
            // concurrent polls: tid0 on f1, tid64 on f2 (ring back-pressure)
            if (tid == 0  && s >= 1)    wait_flag<1>(&f1[s - 1], L1NB, 40000000L);
            if (tid == 64 && s >= RING) wait_flag<1>(&f2[s - RING], L2NB, 40000000L);
            __syncthreads();

            f32x4 acc[4];
            #pragma unroll
            for (int t = 0; t < 4; ++t) acc[t] = (f32x4){0.f,0.f,0.f,0.f};
            if (s > 0) {
                const bf16* arow = y1r + (size_t)((s - 1) & (RING - 1)) * BH
                                       + (size_t)mrow * HIDDEN + q * 8;
                bf16x8 af[32];
                #pragma unroll
                for (int k = 0; k < 32; ++k) ld_sys_b128(&af[k], arow + k * 32);
                vm_drain();
                #pragma unroll
                for (int k = 0; k < 32; ++k) {
                    const int chb = k * 4 + q;
                    #pragma unroll
                    for (int t = 0; t < 4; ++t) {
                        const int row = t * 16 + l15;
                        bf16x8 bw = *(const bf16x8*)&lds[(size_t)((row << 7) + (chb ^ (row & 7))) * 8];
                        acc[t] = __builtin_amdgcn_mfma_f32_16x16x32_bf16(af[k], bw, acc[t], 0, 0, 0);
                    }
                }
            }
            // epilogue: tanh -> LDS transpose stage -> coalesced 16B sc0sc1 stores
            #pragma unroll
            for (int t = 0; t < 4; ++t)
                #pragma unroll
                for (int r = 0; r < 4; ++r) {
                    const int b = wave * 16 + q * 4 + r;
                    cb[b * 64 + t * 16 + l15] =
                        __float2bfloat16(tanhf(acc[t][r] + breg[t] + xg[t][r]));
                }
            __syncthreads();
            bf16* outb = y1r + (size_t)(s & (RING - 1)) * BH;
            #pragma unroll
            for (int it = 0; it < 2; ++it) {
                const int c = it * 256 + tid;          // 0..511
                const int row = c >> 3, off = (c & 7) * 8;
                st_sys_b128(outb + (size_t)row * HIDDEN + n0 + off,
                            *(const bf16x8*)&cb[row * 64 + off]);
            }
            vm_drain();        // stores acked at MALL before the flag
            __syncthreads();
            if (tid == 0)
                __hip_atomic_fetch_add(&f1[s], 1, __ATOMIC_RELEASE, __HIP_MEMORY_SCOPE_AGENT);
        }
    } else {
        // ================= layer 2: 32 cols, K=2048 =================
        const int n0 = (bid - L1NB) * 32;
        // stage [wih2|whh2] slice: 32 rows x 256 chunks
        for (int idx = tid; idx < 32 * 256; idx += 256) {
            const int row = idx >> 8, c = idx & 255;
            const bf16* W = (c < 128) ? wih2 : whh2;
            *(bf16x8*)&lds[(size_t)((row << 8) + (c ^ (row & 7))) * 8] =
                *(const bf16x8*)(W + (size_t)(n0 + row) * HIDDEN + (c & 127) * 8);
        }
        __syncthreads();

        float breg[2];
        #pragma unroll
        for (int t = 0; t < 2; ++t) breg[t] = bias2[n0 + t * 16 + l15];
        bf16* cb = lds + 65536;   // 4 KB transpose stage

        for (int st = 0; st < SEQ; ++st) {
            if (tid == 0)              wait_flag<1>(&f1[st], L1NB, 40000000L);
            if (tid == 64 && st >= 1)  wait_flag<1>(&f2[st - 1], L2NB, 40000000L);
            __syncthreads();

            f32x4 acc[2];
            #pragma unroll
            for (int t = 0; t < 2; ++t) acc[t] = (f32x4){0.f,0.f,0.f,0.f};

            // pass 0: input contribution y1[st] (chunks 0..127)
            {
                const bf16* arow = y1r + (size_t)(st & (RING - 1)) * BH
                                       + (size_t)mrow * HIDDEN + q * 8;
                bf16x8 af[32];
                #pragma unroll
                for (int k = 0; k < 32; ++k) ld_sys_b128(&af[k], arow + k * 32);
                vm_drain();
                #pragma unroll
                for (int k = 0; k < 32; ++k) {
                    const int chb = k * 4 + q;
                    #pragma unroll
                    for (int t = 0; t < 2; ++t) {
                        const int row = t * 16 + l15;
                        bf16x8 bw = *(const bf16x8*)&lds[(size_t)((row << 8) + (chb ^ (row & 7))) * 8];
                        acc[t] = __builtin_amdgcn_mfma_f32_16x16x32_bf16(af[k], bw, acc[t], 0, 0, 0);
                    }
                }
            }
            // pass 1: recurrent contribution y2[st-1] (chunks 128..255)
            if (st > 0) {
                const bf16* arow = y2 + (size_t)(st - 1) * BH
                                      + (size_t)mrow * HIDDEN + q * 8;
                bf16x8 af[32];
                #pragma unroll
                for (int k = 0; k < 32; ++k) ld_sys_b128(&af[k], arow + k * 32);
                vm_drain();
                #pragma unroll
                for (int k = 0; k < 32; ++k) {
                    const int chb = 128 + k * 4 + q;
                    #pragma unroll
                    for (int t = 0; t < 2; ++t) {
                        const int row = t * 16 + l15;
                        bf16x8 bw = *(const bf16x8*)&lds[(size_t)((row << 8) + (chb ^ (row & 7))) * 8];
                        acc[t] = __builtin_amdgcn_mfma_f32_16x16x32_bf16(af[k], bw, acc[t], 0, 0, 0);
                    }
                }
            }
            #pragma unroll
            for (int t = 0; t < 2; ++t)
                #pragma unroll
                for (int r = 0; r < 4; ++r) {
                    const int b = wave * 16 + q * 4 + r;
                    cb[b * 32 + t * 16 + l15] =
                        __float2bfloat16(tanhf(acc[t][r] + breg[t]));
                }
            __syncthreads();
            {
                bf16* outb = y2 + (size_t)st * BH;
                const int row = tid >> 2, off = (tid & 3) * 8;
                st_sys_b128(outb + (size_t)row * HIDDEN + n0 + off,
                            *(const bf16x8*)&cb[row * 32 + off]);
            }
            vm_drain();
            __syncthreads();
            if (tid == 0)
                __hip_atomic_fetch_add(&f2[st], 1, __ATOMIC_RELEASE, __HIP_MEMORY_SCOPE_AGENT);
        }
    }
}

// ---------------------------------------------------------------------------
// Final projection (separate dispatch, as in the 2360us baseline where it was
// L2-friendly): ans = y2 @ W_fc^T + b_fc -> (8192 x 5000). Block 64M x 256N
// (wave tile 32x128). Grid x=bm so the 512 KB B-slice stays L2-resident
// across the 128 row-blocks. C staged in LDS for coalesced stores.
// Kernel-boundary acquire invalidates L2, so y2 (at MALL) is read correctly.
// ---------------------------------------------------------------------------
__global__ __launch_bounds__(256) void proj(
    const bf16* __restrict__ y2, const bf16* __restrict__ Wfc,
    const float* __restrict__ bfc, void* __restrict__ outp,
    const void* __restrict__ det)
{
    __shared__ bf16 cbuf[64 * 256];      // 32 KB C staging
    const int bm = blockIdx.x;           // 128 row tiles
    const int bn = blockIdx.y;           // 20 col tiles of 256
    const int wave = threadIdx.x >> 6;
    const int lane = threadIdx.x & 63;
    const int q = lane >> 4, l15 = lane & 15;
    const int wm = wave & 1, wn = wave >> 1;
    const int m0 = bm * 64 + wm * 32;
    const int n0 = bn * 256 + wn * 128;

    f32x4 acc[2][8];
    #pragma unroll
    for (int i = 0; i < 2; ++i)
        #pragma unroll
        for (int t = 0; t < 8; ++t) acc[i][t] = (f32x4){0.f,0.f,0.f,0.f};

    const bf16x8 zf = (bf16x8){0,0,0,0,0,0,0,0};
    const bf16* a0p = y2 + (size_t)(m0 + l15) * HIDDEN + q * 8;
    const bf16* a1p = a0p + (size_t)16 * HIDDEN;

    for (int k0 = 0; k0 < HIDDEN; k0 += 32) {
        bf16x8 af0 = *(const bf16x8*)(a0p + k0);
        bf16x8 af1 = *(const bf16x8*)(a1p + k0);
        #pragma unroll
        for (int t = 0; t < 8; ++t) {
            const int n = n0 + t * 16 + l15;
            bf16x8 bw = (n < VOCAB)
                ? *(const bf16x8*)(Wfc + (size_t)n * HIDDEN + k0 + q * 8) : zf;
            acc[0][t] = __builtin_amdgcn_mfma_f32_16x16x32_bf16(af0, bw, acc[0][t], 0, 0, 0);
            acc[1][t] = __builtin_amdgcn_mfma_f32_16x16x32_bf16(af1, bw, acc[1][t], 0, 0, 0);
        }
    }

    const bool f32out = detect_fp32(det);

    if (f32out) {
        #pragma unroll
        for (int t = 0; t < 8; ++t) {
            const int col = n0 + t * 16 + l15;
            if (col >= VOCAB) continue;
            const float bias = bfc[col];
            #pragma unroll
            for (int i = 0; i < 2; ++i)
                #pragma unroll
                for (int r = 0; r < 4; ++r) {
                    const int row = m0 + i * 16 + q * 4 + r;
                    ((float*)outp)[(size_t)row * VOCAB + col] = acc[i][t][r] + bias;
                }
        }
        return;
    }

    // bf16 path: stage in LDS, store coalesced 16B/lane full lines.
    #pragma unroll
    for (int t = 0; t < 8; ++t) {
        const int col  = n0 + t * 16 + l15;
        const int cloc = wn * 128 + t * 16 + l15;
        const float bias = (col < VOCAB) ? bfc[col] : 0.f;
        #pragma unroll
        for (int i = 0; i < 2; ++i)
            #pragma unroll
            for (int r = 0; r < 4; ++r) {
                const int rloc = wm * 32 + i * 16 + q * 4 + r;
                cbuf[rloc * 256 + cloc] = __float2bfloat16(acc[i][t][r] + bias);
            }
    }
    __syncthreads();
    bf16* ob = (bf16*)outp;
    for (int cidx = threadIdx.x; cidx < 64 * 32; cidx += 256) {
        const int row = cidx >> 5;
        const int c8  = (cidx & 31) * 8;
        const int gcol = bn * 256 + c8;          // VOCAB % 8 == 0: chunk all-in/out
        if (gcol < VOCAB)
            *(bf16x8*)(ob + (size_t)(bm * 64 + row) * VOCAB + gcol) =
                *(const bf16x8*)&cbuf[row * 256 + c8];
    }
}

__global__ __launch_bounds__(256) void state_copy(
    const bf16* __restrict__ y1r, const bf16* __restrict__ y2,
    void* __restrict__ outp, const void* __restrict__ det)
{
    const bool f32out = detect_fp32(det);
    const int t = blockIdx.x * blockDim.x + threadIdx.x;
    const int BH = BATCH * HIDDEN;
    const size_t ofs = (size_t)SEQ * BATCH * VOCAB;
    float v;
    if (t < BH) v = b2f(y1r[(size_t)((SEQ - 1) & (RING - 1)) * BH + t]);
    else        v = b2f(y2[(size_t)(SEQ - 1) * BH + (t - BH)]);
    if (f32out) ((float*)outp)[ofs + t] = v;
    else        ((bf16*)outp)[ofs + t] = __float2bfloat16(v);
}

extern "C" void kernel_launch(void* const* d_in, const int* in_sizes, int n_in,
                              void* d_out, int out_size, void* d_ws, size_t ws_size,
                              hipStream_t stream) {
    const int*  x       = (const int*)d_in[0];
    const void* Wih1raw = d_in[1];
    const void* Whh1raw = d_in[2];
    const void* bih1    = d_in[3];
    const void* bhh1    = d_in[4];
    const void* Wih2raw = d_in[5];
    const void* Whh2raw = d_in[6];
    const void* bih2    = d_in[7];
    const void* bhh2    = d_in[8];
    const void* Wfcraw  = d_in[9];
    const void* bfcraw  = d_in[10];

    // ws layout: flags (1 KB), bf16 arrays, fp32 biases (~34.2 MB total)
    char* wsb = (char*)d_ws;
    int*   f1    = (int*)wsb;                                    // SEQ ints
    int*   f2    = f1 + SEQ;                                     // SEQ ints
    bf16*  y2    = (bf16*)(wsb + 1024);
    bf16*  y1r   = y2   + (size_t)SEQ * BATCH * HIDDEN;          // RING*B*H
    bf16*  whh1  = y1r  + (size_t)RING * BATCH * HIDDEN;
    bf16*  wih2  = whh1 + (size_t)HIDDEN * HIDDEN;
    bf16*  whh2  = wih2 + (size_t)HIDDEN * HIDDEN;
    bf16*  wfcb  = whh2 + (size_t)HIDDEN * HIDDEN;
    float* bias1 = (float*)(wfcb + (size_t)VOCAB * HIDDEN);
    float* bias2 = bias1 + HIDDEN;
    float* bfcf  = bias2 + HIDDEN;

    // Allow >128K dynamic LDS (host-side attribute; graph-capture-safe).
    static bool lds_ok = false;
    if (!lds_ok) {
        (void)hipFuncSetAttribute((const void*)rnn_persistent,
                                  hipFuncAttributeMaxDynamicSharedMemorySize, LDS_BYTES);
        lds_ok = true;
    }

    (void)hipMemsetAsync(f1, 0, 2 * SEQ * sizeof(int), stream);

    const int HH = HIDDEN * HIDDEN, VH = VOCAB * HIDDEN;
    convert_w<<<(HH + 1023) / 1024, 256, 0, stream>>>(Whh1raw, whh1, HH, Wih1raw);
    convert_w<<<(HH + 1023) / 1024, 256, 0, stream>>>(Wih2raw, wih2, HH, Wih1raw);
    convert_w<<<(HH + 1023) / 1024, 256, 0, stream>>>(Whh2raw, whh2, HH, Wih1raw);
    convert_w<<<(VH + 1023) / 1024, 256, 0, stream>>>(Wfcraw,  wfcb, VH, Wih1raw);
    make_bias<<<(HIDDEN + 255) / 256, 256, 0, stream>>>(bih1, bhh1, bias1, HIDDEN, Wih1raw);
    make_bias<<<(HIDDEN + 255) / 256, 256, 0, stream>>>(bih2, bhh2, bias2, HIDDEN, Wih1raw);
    make_bias<<<(VOCAB + 255) / 256, 256, 0, stream>>>(bfcraw, nullptr, bfcf, VOCAB, Wih1raw);

    // 48-block decoupled recurrence, UNLOADED memory system (R4 lesson).
    rnn_persistent<<<NBLK, 256, LDS_BYTES, stream>>>(x, Wih1raw, whh1, wih2, whh2,
                                                     bias1, bias2, y1r, y2, f1, f2);

    proj<<<dim3(128, 20), 256, 0, stream>>>(y2, wfcb, bfcf, d_out, Wih1raw);
    state_copy<<<(2 * BATCH * HIDDEN) / 256, 256, 0, stream>>>(y1r, y2, d_out, Wih1raw);
}

// Round 7
// 2049.813 us; speedup vs baseline: 1.7019x; 1.0944x over previous
//
#include <hip/hip_runtime.h>
#include <hip/hip_bf16.h>

#define VOCAB 5000
#define HIDDEN 1024
#define SEQ 128
#define BATCH 64
#define L1NB 16   // layer-1 blocks, 64 cols each
#define L2NB 32   // layer-2 blocks, 32 cols each
#define NBLK (L1NB + L2NB)
#define LDS_BYTES 139264

typedef __hip_bfloat16 bf16;
typedef short bf16x8 __attribute__((ext_vector_type(8)));   // 8 bf16 = 4 VGPRs (MFMA A/B frag)
typedef float f32x4 __attribute__((ext_vector_type(4)));    // MFMA C/D frag

__device__ __forceinline__ float b2f(bf16 v) { return __bfloat162float(v); }

// ---------------------------------------------------------------------------
// Dtype self-detection: low 16-bit halves of fp32 weights decode as bf16 with
// exp>=127 ~50% of the time; real bf16 weights (|w|<=0.03) never do.
// ---------------------------------------------------------------------------
__device__ __forceinline__ bool detect_fp32(const void* w) {
    const unsigned* p = (const unsigned*)w;
    unsigned big = 0;
    #pragma unroll
    for (int i = 0; i < 64; ++i) {
        unsigned e = (p[i] >> 7) & 0xFFu;
        big |= (e >= 127u) ? 1u : 0u;
    }
    return big != 0;
}

__global__ __launch_bounds__(256) void convert_w(const void* __restrict__ src,
                                                 bf16* __restrict__ dst, int n,
                                                 const void* __restrict__ det) {
    const bool f32 = detect_fp32(det);
    int i = (blockIdx.x * 256 + threadIdx.x) * 4;
    if (f32) {
        const float* s = (const float*)src;
        #pragma unroll
        for (int j = 0; j < 4; ++j) if (i + j < n) dst[i + j] = __float2bfloat16(s[i + j]);
    } else {
        const bf16* s = (const bf16*)src;
        #pragma unroll
        for (int j = 0; j < 4; ++j) if (i + j < n) dst[i + j] = s[i + j];
    }
}

__global__ __launch_bounds__(256) void make_bias(const void* __restrict__ a,
                                                 const void* __restrict__ b,
                                                 float* __restrict__ dst, int n,
                                                 const void* __restrict__ det) {
    const bool f32 = detect_fp32(det);
    int i = blockIdx.x * 256 + threadIdx.x;
    if (i >= n) return;
    float v = f32 ? ((const float*)a)[i] : b2f(((const bf16*)a)[i]);
    if (b)  v += f32 ? ((const float*)b)[i] : b2f(((const bf16*)b)[i]);
    dst[i] = v;
}

// ---------------------------------------------------------------------------
// Producer side: sc0sc1 write-through 16B stores (bypass L1+L2, land at the
// MALL coherence point). Consumers use NORMAL CACHED loads — safe because
// every y1/y2 address is write-once-within-the-kernel and first read only
// after its flag (R5 lesson: uncached sc0sc1 READS put ~10 MB/step of MALL
// streaming inside the serial chain; cached reads share fetches per-XCD).
// Stale lines from the previous bench iteration are dropped by the kernel-
// launch acquire (proven by R5: proj read sc0sc1-written y2 via cached loads
// correctly over 50 iterations).
// ---------------------------------------------------------------------------
__device__ __forceinline__ void st_sys_b128(void* p, bf16x8 v) {
    asm volatile("global_store_dwordx4 %0, %1, off sc0 sc1" :: "v"(p), "v"(v) : "memory");
}
__device__ __forceinline__ void vm_drain() {
    asm volatile("s_waitcnt vmcnt(0)" ::: "memory");
    __builtin_amdgcn_sched_barrier(0);
}

// Relaxed-only poll (agent-scope atomics execute at the coherence point).
// BOUNDED TIGHTLY (R6 lesson): worst case ~50 ms/wait, ~8 s whole-kernel,
// far under any watchdog — a broken protocol surfaces as an absmax failure
// with a profile, never a container-killing hang. SLP is a template param
// (s_sleep needs a compile-time constant).
template <int SLP>
__device__ __forceinline__ void wait_flag(int* flag, int target, int maxit) {
    int n = 0;
    while (__hip_atomic_load(flag, __ATOMIC_RELAXED, __HIP_MEMORY_SCOPE_AGENT) < target) {
        __builtin_amdgcn_s_sleep(SLP);
        if (++n > maxit) return;
    }
}

// ---------------------------------------------------------------------------
// Decoupled recurrence (48 blocks, separate from proj per R4 lesson).
//   blocks  0..15 : layer-1, 64 hidden cols each
//   blocks 16..47 : layer-2, 32 hidden cols each
// R6 design (first real run this round):
//  * y1 is a FULL (S,B,H) write-once buffer (in d_out scratch) -> no ring,
//    no f2 back-pressure in L1; L1 chain fully decoupled, runs ahead.
//  * consumers read y1/y2 with CACHED loads (XCD-L2 shared) instead of
//    sc0sc1 uncached streaming.
//  * L2 step split: phase A (pass-0, y1 input contribution) runs off-chain
//    (f1[st] is set well in advance); only phase B (y2[st-1] @ Whh2) is on
//    the serial f2 chain — K=1024 instead of 2048 on the critical path.
// ---------------------------------------------------------------------------
__global__ __launch_bounds__(256, 1) void rnn_persistent(
    const int*  __restrict__ x,        // (S,B) int32
    const void* __restrict__ Wih1raw,  // (H,V) fp32 or bf16 (gather + detect)
    const bf16* __restrict__ whh1,     // (H,H) ws bf16
    const bf16* __restrict__ wih2,     // (H,H) ws bf16
    const bf16* __restrict__ whh2,     // (H,H) ws bf16
    const float* __restrict__ bias1,   // (H)
    const float* __restrict__ bias2,   // (H)
    bf16* __restrict__ y1,             // (S,B,H) layer-1 history (d_out scratch)
    bf16* __restrict__ y2,             // (S,B,H) layer-2 history
    int* __restrict__ f1,              // (SEQ) flags
    int* __restrict__ f2)              // (SEQ) flags
{
    extern __shared__ bf16 lds[];      // 139264 B (128K weights + 8K cbuf)
    const int bid  = blockIdx.x;
    const int tid  = threadIdx.x;
    const int wave = tid >> 6;
    const int lane = tid & 63;
    const int q    = lane >> 4;
    const int l15  = lane & 15;
    const size_t BH = (size_t)BATCH * HIDDEN;
    const int  mrow  = wave * 16 + l15;          // batch row for A frag

    if (bid < L1NB) {
        // ================= layer 1: 64 cols =================
        const bool f32in = detect_fp32(Wih1raw);
        const int n0 = bid * 64;
        // stage whh1 slice: 64 rows x 128 chunks (16B), swizzle c ^ (row&7)
        for (int idx = tid; idx < 64 * 128; idx += 256) {
            const int row = idx >> 7, c = idx & 127;
            *(bf16x8*)&lds[(size_t)((row << 7) + (c ^ (row & 7))) * 8] =
                *(const bf16x8*)(whh1 + (size_t)(n0 + row) * HIDDEN + c * 8);
        }
        __syncthreads();

        float breg[4];
        #pragma unroll
        for (int t = 0; t < 4; ++t) breg[t] = bias1[n0 + t * 16 + l15];
        bf16* cb = lds + 65536;   // 8 KB transpose stage (byte offset 128K)

        for (int s = 0; s < SEQ; ++s) {
            // embedding gather: cached, L2-hot; issued before the wait.
            float xg[4][4];
            {
                int xv[4];
                #pragma unroll
                for (int r = 0; r < 4; ++r) xv[r] = x[s * BATCH + wave * 16 + q * 4 + r];
                #pragma unroll
                for (int t = 0; t < 4; ++t)
                    #pragma unroll
                    for (int r = 0; r < 4; ++r) {
                        const size_t gi = (size_t)(n0 + t * 16 + l15) * VOCAB + xv[r];
                        xg[t][r] = f32in ? ((const float*)Wih1raw)[gi]
                                         : b2f(((const bf16*)Wih1raw)[gi]);
                    }
            }
            if (tid == 0 && s >= 1) wait_flag<1>(&f1[s - 1], L1NB, 300000);
            __syncthreads();

            f32x4 acc[4];
            #pragma unroll
            for (int t = 0; t < 4; ++t) acc[t] = (f32x4){0.f,0.f,0.f,0.f};
            if (s > 0) {
                // cached reads: 2 L1-blocks/XCD share each y1[s-1] line
                const bf16* arow = y1 + (size_t)(s - 1) * BH
                                      + (size_t)mrow * HIDDEN + q * 8;
                #pragma unroll
                for (int k = 0; k < 32; ++k) {
                    bf16x8 af = *(const bf16x8*)(arow + k * 32);
                    const int chb = k * 4 + q;
                    #pragma unroll
                    for (int t = 0; t < 4; ++t) {
                        const int row = t * 16 + l15;
                        bf16x8 bw = *(const bf16x8*)&lds[(size_t)((row << 7) + (chb ^ (row & 7))) * 8];
                        acc[t] = __builtin_amdgcn_mfma_f32_16x16x32_bf16(af, bw, acc[t], 0, 0, 0);
                    }
                }
            }
            // epilogue: tanh -> LDS transpose -> coalesced 16B sc0sc1 stores
            #pragma unroll
            for (int t = 0; t < 4; ++t)
                #pragma unroll
                for (int r = 0; r < 4; ++r) {
                    const int b = wave * 16 + q * 4 + r;
                    cb[b * 64 + t * 16 + l15] =
                        __float2bfloat16(tanhf(acc[t][r] + breg[t] + xg[t][r]));
                }
            __syncthreads();
            bf16* outb = y1 + (size_t)s * BH;
            #pragma unroll
            for (int it = 0; it < 2; ++it) {
                const int c = it * 256 + tid;          // 0..511
                const int row = c >> 3, off = (c & 7) * 8;
                st_sys_b128(outb + (size_t)row * HIDDEN + n0 + off,
                            *(const bf16x8*)&cb[row * 64 + off]);
            }
            vm_drain();        // stores acked at MALL before the flag
            __syncthreads();
            if (tid == 0)
                __hip_atomic_fetch_add(&f1[s], 1, __ATOMIC_RELEASE, __HIP_MEMORY_SCOPE_AGENT);
        }
    } else {
        // ================= layer 2: 32 cols =================
        const int n0 = (bid - L1NB) * 32;
        // stage [wih2|whh2] slice: 32 rows x 256 chunks
        for (int idx = tid; idx < 32 * 256; idx += 256) {
            const int row = idx >> 8, c = idx & 255;
            const bf16* W = (c < 128) ? wih2 : whh2;
            *(bf16x8*)&lds[(size_t)((row << 8) + (c ^ (row & 7))) * 8] =
                *(const bf16x8*)(W + (size_t)(n0 + row) * HIDDEN + (c & 127) * 8);
        }
        __syncthreads();

        float breg[2];
        #pragma unroll
        for (int t = 0; t < 2; ++t) breg[t] = bias2[n0 + t * 16 + l15];
        bf16* cb = lds + 65536;   // 4 KB transpose stage

        for (int st = 0; st < SEQ; ++st) {
            // ---- phase A (off-chain): input contribution y1[st] @ Wih2 ----
            // 32 pollers on one line: gentler s_sleep(4) backoff.
            if (tid == 0) wait_flag<4>(&f1[st], L1NB, 100000);
            __syncthreads();

            f32x4 acc[2];
            #pragma unroll
            for (int t = 0; t < 2; ++t) acc[t] = (f32x4){0.f,0.f,0.f,0.f};
            {
                const bf16* arow = y1 + (size_t)st * BH
                                      + (size_t)mrow * HIDDEN + q * 8;
                #pragma unroll
                for (int k = 0; k < 32; ++k) {
                    bf16x8 af = *(const bf16x8*)(arow + k * 32);
                    const int chb = k * 4 + q;
                    #pragma unroll
                    for (int t = 0; t < 2; ++t) {
                        const int row = t * 16 + l15;
                        bf16x8 bw = *(const bf16x8*)&lds[(size_t)((row << 8) + (chb ^ (row & 7))) * 8];
                        acc[t] = __builtin_amdgcn_mfma_f32_16x16x32_bf16(af, bw, acc[t], 0, 0, 0);
                    }
                }
            }
            // ---- phase B (serial chain): recurrent y2[st-1] @ Whh2 ----
            if (tid == 0 && st >= 1) wait_flag<1>(&f2[st - 1], L2NB, 300000);
            __syncthreads();
            if (st > 0) {
                const bf16* arow = y2 + (size_t)(st - 1) * BH
                                      + (size_t)mrow * HIDDEN + q * 8;
                #pragma unroll
                for (int k = 0; k < 32; ++k) {
                    bf16x8 af = *(const bf16x8*)(arow + k * 32);
                    const int chb = 128 + k * 4 + q;
                    #pragma unroll
                    for (int t = 0; t < 2; ++t) {
                        const int row = t * 16 + l15;
                        bf16x8 bw = *(const bf16x8*)&lds[(size_t)((row << 8) + (chb ^ (row & 7))) * 8];
                        acc[t] = __builtin_amdgcn_mfma_f32_16x16x32_bf16(af, bw, acc[t], 0, 0, 0);
                    }
                }
            }
            #pragma unroll
            for (int t = 0; t < 2; ++t)
                #pragma unroll
                for (int r = 0; r < 4; ++r) {
                    const int b = wave * 16 + q * 4 + r;
                    cb[b * 32 + t * 16 + l15] =
                        __float2bfloat16(tanhf(acc[t][r] + breg[t]));
                }
            __syncthreads();
            {
                bf16* outb = y2 + (size_t)st * BH;
                const int row = tid >> 2, off = (tid & 3) * 8;
                st_sys_b128(outb + (size_t)row * HIDDEN + n0 + off,
                            *(const bf16x8*)&cb[row * 32 + off]);
            }
            vm_drain();
            __syncthreads();
            if (tid == 0)
                __hip_atomic_fetch_add(&f2[st], 1, __ATOMIC_RELEASE, __HIP_MEMORY_SCOPE_AGENT);
        }
    }
}

// ---------------------------------------------------------------------------
// Final projection (separate dispatch, L2-friendly grid as in R5):
// ans = y2 @ W_fc^T + b_fc -> (8192 x 5000). Runs AFTER state_copy because
// y1 scratch lives in the logits region of d_out and proj overwrites it.
// ---------------------------------------------------------------------------
__global__ __launch_bounds__(256) void proj(
    const bf16* __restrict__ y2, const bf16* __restrict__ Wfc,
    const float* __restrict__ bfc, void* __restrict__ outp,
    const void* __restrict__ det)
{
    __shared__ bf16 cbuf[64 * 256];      // 32 KB C staging
    const int bm = blockIdx.x;           // 128 row tiles
    const int bn = blockIdx.y;           // 20 col tiles of 256
    const int wave = threadIdx.x >> 6;
    const int lane = threadIdx.x & 63;
    const int q = lane >> 4, l15 = lane & 15;
    const int wm = wave & 1, wn = wave >> 1;
    const int m0 = bm * 64 + wm * 32;
    const int n0 = bn * 256 + wn * 128;

    f32x4 acc[2][8];
    #pragma unroll
    for (int i = 0; i < 2; ++i)
        #pragma unroll
        for (int t = 0; t < 8; ++t) acc[i][t] = (f32x4){0.f,0.f,0.f,0.f};

    const bf16x8 zf = (bf16x8){0,0,0,0,0,0,0,0};
    const bf16* a0p = y2 + (size_t)(m0 + l15) * HIDDEN + q * 8;
    const bf16* a1p = a0p + (size_t)16 * HIDDEN;

    for (int k0 = 0; k0 < HIDDEN; k0 += 32) {
        bf16x8 af0 = *(const bf16x8*)(a0p + k0);
        bf16x8 af1 = *(const bf16x8*)(a1p + k0);
        #pragma unroll
        for (int t = 0; t < 8; ++t) {
            const int n = n0 + t * 16 + l15;
            bf16x8 bw = (n < VOCAB)
                ? *(const bf16x8*)(Wfc + (size_t)n * HIDDEN + k0 + q * 8) : zf;
            acc[0][t] = __builtin_amdgcn_mfma_f32_16x16x32_bf16(af0, bw, acc[0][t], 0, 0, 0);
            acc[1][t] = __builtin_amdgcn_mfma_f32_16x16x32_bf16(af1, bw, acc[1][t], 0, 0, 0);
        }
    }

    const bool f32out = detect_fp32(det);

    if (f32out) {
        #pragma unroll
        for (int t = 0; t < 8; ++t) {
            const int col = n0 + t * 16 + l15;
            if (col >= VOCAB) continue;
            const float bias = bfc[col];
            #pragma unroll
            for (int i = 0; i < 2; ++i)
                #pragma unroll
                for (int r = 0; r < 4; ++r) {
                    const int row = m0 + i * 16 + q * 4 + r;
                    ((float*)outp)[(size_t)row * VOCAB + col] = acc[i][t][r] + bias;
                }
        }
        return;
    }

    // bf16 path: stage in LDS, store coalesced 16B/lane full lines.
    #pragma unroll
    for (int t = 0; t < 8; ++t) {
        const int col  = n0 + t * 16 + l15;
        const int cloc = wn * 128 + t * 16 + l15;
        const float bias = (col < VOCAB) ? bfc[col] : 0.f;
        #pragma unroll
        for (int i = 0; i < 2; ++i)
            #pragma unroll
            for (int r = 0; r < 4; ++r) {
                const int rloc = wm * 32 + i * 16 + q * 4 + r;
                cbuf[rloc * 256 + cloc] = __float2bfloat16(acc[i][t][r] + bias);
            }
    }
    __syncthreads();
    bf16* ob = (bf16*)outp;
    for (int cidx = threadIdx.x; cidx < 64 * 32; cidx += 256) {
        const int row = cidx >> 5;
        const int c8  = (cidx & 31) * 8;
        const int gcol = bn * 256 + c8;          // VOCAB % 8 == 0: chunk all-in/out
        if (gcol < VOCAB)
            *(bf16x8*)(ob + (size_t)(bm * 64 + row) * VOCAB + gcol) =
                *(const bf16x8*)&cbuf[row * 256 + c8];
    }
}

// Runs BEFORE proj (y1 scratch is in d_out's logits region).
__global__ __launch_bounds__(256) void state_copy(
    const bf16* __restrict__ y1, const bf16* __restrict__ y2,
    void* __restrict__ outp, const void* __restrict__ det)
{
    const bool f32out = detect_fp32(det);
    const int t = blockIdx.x * blockDim.x + threadIdx.x;
    const int BH = BATCH * HIDDEN;
    const size_t ofs = (size_t)SEQ * BATCH * VOCAB;
    float v;
    if (t < BH) v = b2f(y1[(size_t)(SEQ - 1) * BH + t]);
    else        v = b2f(y2[(size_t)(SEQ - 1) * BH + (t - BH)]);
    if (f32out) ((float*)outp)[ofs + t] = v;
    else        ((bf16*)outp)[ofs + t] = __float2bfloat16(v);
}

extern "C" void kernel_launch(void* const* d_in, const int* in_sizes, int n_in,
                              void* d_out, int out_size, void* d_ws, size_t ws_size,
                              hipStream_t stream) {
    const int*  x       = (const int*)d_in[0];
    const void* Wih1raw = d_in[1];
    const void* Whh1raw = d_in[2];
    const void* bih1    = d_in[3];
    const void* bhh1    = d_in[4];
    const void* Wih2raw = d_in[5];
    const void* Whh2raw = d_in[6];
    const void* bih2    = d_in[7];
    const void* bhh2    = d_in[8];
    const void* Wfcraw  = d_in[9];
    const void* bfcraw  = d_in[10];

    // ws layout: flags (1 KB), bf16 arrays, fp32 biases (~33 MB total).
    // y1 full (S,B,H) history lives in d_out's logits region (16.8 MB scratch,
    // overwritten by proj at the end) so ws footprint does not grow.
    char* wsb = (char*)d_ws;
    int*   f1    = (int*)wsb;                                    // SEQ ints
    int*   f2    = f1 + SEQ;                                     // SEQ ints
    bf16*  y2    = (bf16*)(wsb + 1024);
    bf16*  whh1  = y2   + (size_t)SEQ * BATCH * HIDDEN;
    bf16*  wih2  = whh1 + (size_t)HIDDEN * HIDDEN;
    bf16*  whh2  = wih2 + (size_t)HIDDEN * HIDDEN;
    bf16*  wfcb  = whh2 + (size_t)HIDDEN * HIDDEN;
    float* bias1 = (float*)(wfcb + (size_t)VOCAB * HIDDEN);
    float* bias2 = bias1 + HIDDEN;
    float* bfcf  = bias2 + HIDDEN;
    bf16*  y1    = (bf16*)d_out;                                 // scratch

    // Allow >128K dynamic LDS (host-side attribute; graph-capture-safe).
    static bool lds_ok = false;
    if (!lds_ok) {
        (void)hipFuncSetAttribute((const void*)rnn_persistent,
                                  hipFuncAttributeMaxDynamicSharedMemorySize, LDS_BYTES);
        lds_ok = true;
    }

    (void)hipMemsetAsync(f1, 0, 2 * SEQ * sizeof(int), stream);

    const int HH = HIDDEN * HIDDEN, VH = VOCAB * HIDDEN;
    convert_w<<<(HH + 1023) / 1024, 256, 0, stream>>>(Whh1raw, whh1, HH, Wih1raw);
    convert_w<<<(HH + 1023) / 1024, 256, 0, stream>>>(Wih2raw, wih2, HH, Wih1raw);
    convert_w<<<(HH + 1023) / 1024, 256, 0, stream>>>(Whh2raw, whh2, HH, Wih1raw);
    convert_w<<<(VH + 1023) / 1024, 256, 0, stream>>>(Wfcraw,  wfcb, VH, Wih1raw);
    make_bias<<<(HIDDEN + 255) / 256, 256, 0, stream>>>(bih1, bhh1, bias1, HIDDEN, Wih1raw);
    make_bias<<<(HIDDEN + 255) / 256, 256, 0, stream>>>(bih2, bhh2, bias2, HIDDEN, Wih1raw);
    make_bias<<<(VOCAB + 255) / 256, 256, 0, stream>>>(bfcraw, nullptr, bfcf, VOCAB, Wih1raw);

    // 48-block decoupled recurrence (cached consumer reads, write-once y1).
    rnn_persistent<<<NBLK, 256, LDS_BYTES, stream>>>(x, Wih1raw, whh1, wih2, whh2,
                                                     bias1, bias2, y1, y2, f1, f2);

    // state_copy BEFORE proj: proj overwrites the y1 scratch region.
    state_copy<<<(2 * BATCH * HIDDEN) / 256, 256, 0, stream>>>(y1, y2, d_out, Wih1raw);
    proj<<<dim3(128, 20), 256, 0, stream>>>(y2, wfcb, bfcf, d_out, Wih1raw);
}

// Round 8
// 2007.224 us; speedup vs baseline: 1.7380x; 1.0212x over previous
//
#include <hip/hip_runtime.h>
#include <hip/hip_bf16.h>

#define VOCAB 5000
#define HIDDEN 1024
#define SEQ 128
#define BATCH 64
#define L1NB 16   // layer-1 blocks, 64 cols each
#define L2NB 32   // layer-2 blocks, 32 cols each
#define NBLK (L1NB + L2NB)
#define LDS_BYTES 139264

typedef __hip_bfloat16 bf16;
typedef short bf16x8 __attribute__((ext_vector_type(8)));   // 8 bf16 = 4 VGPRs (MFMA A/B frag)
typedef float f32x4 __attribute__((ext_vector_type(4)));    // MFMA C/D frag

__device__ __forceinline__ float b2f(bf16 v) { return __bfloat162float(v); }

// ---------------------------------------------------------------------------
// Dtype self-detection: low 16-bit halves of fp32 weights decode as bf16 with
// exp>=127 ~50% of the time; real bf16 weights (|w|<=0.03) never do.
// ---------------------------------------------------------------------------
__device__ __forceinline__ bool detect_fp32(const void* w) {
    const unsigned* p = (const unsigned*)w;
    unsigned big = 0;
    #pragma unroll
    for (int i = 0; i < 64; ++i) {
        unsigned e = (p[i] >> 7) & 0xFFu;
        big |= (e >= 127u) ? 1u : 0u;
    }
    return big != 0;
}

__global__ __launch_bounds__(256) void convert_w(const void* __restrict__ src,
                                                 bf16* __restrict__ dst, int n,
                                                 const void* __restrict__ det) {
    const bool f32 = detect_fp32(det);
    int i = (blockIdx.x * 256 + threadIdx.x) * 4;
    if (f32) {
        const float* s = (const float*)src;
        #pragma unroll
        for (int j = 0; j < 4; ++j) if (i + j < n) dst[i + j] = __float2bfloat16(s[i + j]);
    } else {
        const bf16* s = (const bf16*)src;
        #pragma unroll
        for (int j = 0; j < 4; ++j) if (i + j < n) dst[i + j] = s[i + j];
    }
}

__global__ __launch_bounds__(256) void make_bias(const void* __restrict__ a,
                                                 const void* __restrict__ b,
                                                 float* __restrict__ dst, int n,
                                                 const void* __restrict__ det) {
    const bool f32 = detect_fp32(det);
    int i = blockIdx.x * 256 + threadIdx.x;
    if (i >= n) return;
    float v = f32 ? ((const float*)a)[i] : b2f(((const bf16*)a)[i]);
    if (b)  v += f32 ? ((const float*)b)[i] : b2f(((const bf16*)b)[i]);
    dst[i] = v;
}

// ---------------------------------------------------------------------------
// Producer side: sc0sc1 write-through 16B stores (bypass L1+L2, land at the
// MALL coherence point). Consumers use NORMAL CACHED loads — safe because
// every y1/y2 address is write-once-within-the-kernel and first read only
// after its flag. R8: flag adds are RELAXED — the vmcnt(0) drain already
// guarantees the data is at the coherence point, so the release fence (which
// emits a per-step buffer_wbl2 L2-writeback walk on gfx950) is redundant.
// ---------------------------------------------------------------------------
__device__ __forceinline__ void st_sys_b128(void* p, bf16x8 v) {
    asm volatile("global_store_dwordx4 %0, %1, off sc0 sc1" :: "v"(p), "v"(v) : "memory");
}
__device__ __forceinline__ void vm_drain() {
    asm volatile("s_waitcnt vmcnt(0)" ::: "memory");
    __builtin_amdgcn_sched_barrier(0);
}

// Relaxed-only poll (agent-scope atomics execute at the coherence point).
// BOUNDED TIGHTLY: worst case ~50 ms/wait — a broken protocol surfaces as an
// absmax failure with a profile, never a container-killing hang.
template <int SLP>
__device__ __forceinline__ void wait_flag(int* flag, int target, int maxit) {
    int n = 0;
    while (__hip_atomic_load(flag, __ATOMIC_RELAXED, __HIP_MEMORY_SCOPE_AGENT) < target) {
        __builtin_amdgcn_s_sleep(SLP);
        if (++n > maxit) return;
    }
}

// ---------------------------------------------------------------------------
// Decoupled recurrence (48 blocks, separate from proj per R4 lesson).
//   blocks  0..15 : layer-1, 64 hidden cols each
//   blocks 16..47 : layer-2, 32 hidden cols each
// R8 changes vs R7 (both target the ~9 us/step of unexplained chain cost):
//  * af[32] register staging RESTORED (R7's VGPR=64 showed the compiler kept
//    only ~4 loads in flight -> A-operand read latency-serialized). Cached
//    loads + full-batch issue = one miss latency per pass, not ~8.
//  * flag adds RELAXED (no release) -> no per-step buffer_wbl2 in the chain.
// ---------------------------------------------------------------------------
__global__ __launch_bounds__(256, 1) void rnn_persistent(
    const int*  __restrict__ x,        // (S,B) int32
    const void* __restrict__ Wih1raw,  // (H,V) fp32 or bf16 (gather + detect)
    const bf16* __restrict__ whh1,     // (H,H) ws bf16
    const bf16* __restrict__ wih2,     // (H,H) ws bf16
    const bf16* __restrict__ whh2,     // (H,H) ws bf16
    const float* __restrict__ bias1,   // (H)
    const float* __restrict__ bias2,   // (H)
    bf16* __restrict__ y1,             // (S,B,H) layer-1 history (d_out scratch)
    bf16* __restrict__ y2,             // (S,B,H) layer-2 history
    int* __restrict__ f1,              // (SEQ) flags
    int* __restrict__ f2)              // (SEQ) flags
{
    extern __shared__ bf16 lds[];      // 139264 B (128K weights + 8K cbuf)
    const int bid  = blockIdx.x;
    const int tid  = threadIdx.x;
    const int wave = tid >> 6;
    const int lane = tid & 63;
    const int q    = lane >> 4;
    const int l15  = lane & 15;
    const size_t BH = (size_t)BATCH * HIDDEN;
    const int  mrow  = wave * 16 + l15;          // batch row for A frag

    if (bid < L1NB) {
        // ================= layer 1: 64 cols =================
        const bool f32in = detect_fp32(Wih1raw);
        const int n0 = bid * 64;
        // stage whh1 slice: 64 rows x 128 chunks (16B), swizzle c ^ (row&7)
        for (int idx = tid; idx < 64 * 128; idx += 256) {
            const int row = idx >> 7, c = idx & 127;
            *(bf16x8*)&lds[(size_t)((row << 7) + (c ^ (row & 7))) * 8] =
                *(const bf16x8*)(whh1 + (size_t)(n0 + row) * HIDDEN + c * 8);
        }
        __syncthreads();

        float breg[4];
        #pragma unroll
        for (int t = 0; t < 4; ++t) breg[t] = bias1[n0 + t * 16 + l15];
        bf16* cb = lds + 65536;   // 8 KB transpose stage (byte offset 128K)

        for (int s = 0; s < SEQ; ++s) {
            // embedding gather: cached, L2-hot; issued before the wait.
            float xg[4][4];
            {
                int xv[4];
                #pragma unroll
                for (int r = 0; r < 4; ++r) xv[r] = x[s * BATCH + wave * 16 + q * 4 + r];
                #pragma unroll
                for (int t = 0; t < 4; ++t)
                    #pragma unroll
                    for (int r = 0; r < 4; ++r) {
                        const size_t gi = (size_t)(n0 + t * 16 + l15) * VOCAB + xv[r];
                        xg[t][r] = f32in ? ((const float*)Wih1raw)[gi]
                                         : b2f(((const bf16*)Wih1raw)[gi]);
                    }
            }
            if (tid == 0 && s >= 1) wait_flag<1>(&f1[s - 1], L1NB, 300000);
            __syncthreads();

            f32x4 acc[4];
            #pragma unroll
            for (int t = 0; t < 4; ++t) acc[t] = (f32x4){0.f,0.f,0.f,0.f};
            if (s > 0) {
                const bf16* arow = y1 + (size_t)(s - 1) * BH
                                      + (size_t)mrow * HIDDEN + q * 8;
                // full register staging: 32 cached loads issued back-to-back
                bf16x8 af[32];
                #pragma unroll
                for (int k = 0; k < 32; ++k) af[k] = *(const bf16x8*)(arow + k * 32);
                #pragma unroll
                for (int k = 0; k < 32; ++k) {
                    const int chb = k * 4 + q;
                    #pragma unroll
                    for (int t = 0; t < 4; ++t) {
                        const int row = t * 16 + l15;
                        bf16x8 bw = *(const bf16x8*)&lds[(size_t)((row << 7) + (chb ^ (row & 7))) * 8];
                        acc[t] = __builtin_amdgcn_mfma_f32_16x16x32_bf16(af[k], bw, acc[t], 0, 0, 0);
                    }
                }
            }
            // epilogue: tanh -> LDS transpose -> coalesced 16B sc0sc1 stores
            #pragma unroll
            for (int t = 0; t < 4; ++t)
                #pragma unroll
                for (int r = 0; r < 4; ++r) {
                    const int b = wave * 16 + q * 4 + r;
                    cb[b * 64 + t * 16 + l15] =
                        __float2bfloat16(tanhf(acc[t][r] + breg[t] + xg[t][r]));
                }
            __syncthreads();
            bf16* outb = y1 + (size_t)s * BH;
            #pragma unroll
            for (int it = 0; it < 2; ++it) {
                const int c = it * 256 + tid;          // 0..511
                const int row = c >> 3, off = (c & 7) * 8;
                st_sys_b128(outb + (size_t)row * HIDDEN + n0 + off,
                            *(const bf16x8*)&cb[row * 64 + off]);
            }
            vm_drain();        // stores acked at MALL before the flag
            __syncthreads();
            if (tid == 0)      // RELAXED: drain already ordered the data
                __hip_atomic_fetch_add(&f1[s], 1, __ATOMIC_RELAXED, __HIP_MEMORY_SCOPE_AGENT);
        }
    } else {
        // ================= layer 2: 32 cols =================
        const int n0 = (bid - L1NB) * 32;
        // stage [wih2|whh2] slice: 32 rows x 256 chunks
        for (int idx = tid; idx < 32 * 256; idx += 256) {
            const int row = idx >> 8, c = idx & 255;
            const bf16* W = (c < 128) ? wih2 : whh2;
            *(bf16x8*)&lds[(size_t)((row << 8) + (c ^ (row & 7))) * 8] =
                *(const bf16x8*)(W + (size_t)(n0 + row) * HIDDEN + (c & 127) * 8);
        }
        __syncthreads();

        float breg[2];
        #pragma unroll
        for (int t = 0; t < 2; ++t) breg[t] = bias2[n0 + t * 16 + l15];
        bf16* cb = lds + 65536;   // 4 KB transpose stage

        for (int st = 0; st < SEQ; ++st) {
            // ---- phase A (off-chain): input contribution y1[st] @ Wih2 ----
            if (tid == 0) wait_flag<4>(&f1[st], L1NB, 100000);
            __syncthreads();

            f32x4 acc[2];
            #pragma unroll
            for (int t = 0; t < 2; ++t) acc[t] = (f32x4){0.f,0.f,0.f,0.f};
            {
                const bf16* arow = y1 + (size_t)st * BH
                                      + (size_t)mrow * HIDDEN + q * 8;
                bf16x8 af[32];
                #pragma unroll
                for (int k = 0; k < 32; ++k) af[k] = *(const bf16x8*)(arow + k * 32);
                #pragma unroll
                for (int k = 0; k < 32; ++k) {
                    const int chb = k * 4 + q;
                    #pragma unroll
                    for (int t = 0; t < 2; ++t) {
                        const int row = t * 16 + l15;
                        bf16x8 bw = *(const bf16x8*)&lds[(size_t)((row << 8) + (chb ^ (row & 7))) * 8];
                        acc[t] = __builtin_amdgcn_mfma_f32_16x16x32_bf16(af[k], bw, acc[t], 0, 0, 0);
                    }
                }
            }
            // ---- phase B (serial chain): recurrent y2[st-1] @ Whh2 ----
            if (tid == 0 && st >= 1) wait_flag<1>(&f2[st - 1], L2NB, 300000);
            __syncthreads();
            if (st > 0) {
                const bf16* arow = y2 + (size_t)(st - 1) * BH
                                      + (size_t)mrow * HIDDEN + q * 8;
                bf16x8 af[32];
                #pragma unroll
                for (int k = 0; k < 32; ++k) af[k] = *(const bf16x8*)(arow + k * 32);
                #pragma unroll
                for (int k = 0; k < 32; ++k) {
                    const int chb = 128 + k * 4 + q;
                    #pragma unroll
                    for (int t = 0; t < 2; ++t) {
                        const int row = t * 16 + l15;
                        bf16x8 bw = *(const bf16x8*)&lds[(size_t)((row << 8) + (chb ^ (row & 7))) * 8];
                        acc[t] = __builtin_amdgcn_mfma_f32_16x16x32_bf16(af[k], bw, acc[t], 0, 0, 0);
                    }
                }
            }
            #pragma unroll
            for (int t = 0; t < 2; ++t)
                #pragma unroll
                for (int r = 0; r < 4; ++r) {
                    const int b = wave * 16 + q * 4 + r;
                    cb[b * 32 + t * 16 + l15] =
                        __float2bfloat16(tanhf(acc[t][r] + breg[t]));
                }
            __syncthreads();
            {
                bf16* outb = y2 + (size_t)st * BH;
                const int row = tid >> 2, off = (tid & 3) * 8;
                st_sys_b128(outb + (size_t)row * HIDDEN + n0 + off,
                            *(const bf16x8*)&cb[row * 32 + off]);
            }
            vm_drain();
            __syncthreads();
            if (tid == 0)      // RELAXED: drain already ordered the data
                __hip_atomic_fetch_add(&f2[st], 1, __ATOMIC_RELAXED, __HIP_MEMORY_SCOPE_AGENT);
        }
    }
}

// ---------------------------------------------------------------------------
// Final projection (separate dispatch, L2-friendly grid):
// ans = y2 @ W_fc^T + b_fc -> (8192 x 5000). Runs AFTER state_copy because
// y1 scratch lives in the logits region of d_out and proj overwrites it.
// ---------------------------------------------------------------------------
__global__ __launch_bounds__(256) void proj(
    const bf16* __restrict__ y2, const bf16* __restrict__ Wfc,
    const float* __restrict__ bfc, void* __restrict__ outp,
    const void* __restrict__ det)
{
    __shared__ bf16 cbuf[64 * 256];      // 32 KB C staging
    const int bm = blockIdx.x;           // 128 row tiles
    const int bn = blockIdx.y;           // 20 col tiles of 256
    const int wave = threadIdx.x >> 6;
    const int lane = threadIdx.x & 63;
    const int q = lane >> 4, l15 = lane & 15;
    const int wm = wave & 1, wn = wave >> 1;
    const int m0 = bm * 64 + wm * 32;
    const int n0 = bn * 256 + wn * 128;

    f32x4 acc[2][8];
    #pragma unroll
    for (int i = 0; i < 2; ++i)
        #pragma unroll
        for (int t = 0; t < 8; ++t) acc[i][t] = (f32x4){0.f,0.f,0.f,0.f};

    const bf16x8 zf = (bf16x8){0,0,0,0,0,0,0,0};
    const bf16* a0p = y2 + (size_t)(m0 + l15) * HIDDEN + q * 8;
    const bf16* a1p = a0p + (size_t)16 * HIDDEN;

    for (int k0 = 0; k0 < HIDDEN; k0 += 32) {
        bf16x8 af0 = *(const bf16x8*)(a0p + k0);
        bf16x8 af1 = *(const bf16x8*)(a1p + k0);
        #pragma unroll
        for (int t = 0; t < 8; ++t) {
            const int n = n0 + t * 16 + l15;
            bf16x8 bw = (n < VOCAB)
                ? *(const bf16x8*)(Wfc + (size_t)n * HIDDEN + k0 + q * 8) : zf;
            acc[0][t] = __builtin_amdgcn_mfma_f32_16x16x32_bf16(af0, bw, acc[0][t], 0, 0, 0);
            acc[1][t] = __builtin_amdgcn_mfma_f32_16x16x32_bf16(af1, bw, acc[1][t], 0, 0, 0);
        }
    }

    const bool f32out = detect_fp32(det);

    if (f32out) {
        #pragma unroll
        for (int t = 0; t < 8; ++t) {
            const int col = n0 + t * 16 + l15;
            if (col >= VOCAB) continue;
            const float bias = bfc[col];
            #pragma unroll
            for (int i = 0; i < 2; ++i)
                #pragma unroll
                for (int r = 0; r < 4; ++r) {
                    const int row = m0 + i * 16 + q * 4 + r;
                    ((float*)outp)[(size_t)row * VOCAB + col] = acc[i][t][r] + bias;
                }
        }
        return;
    }

    // bf16 path: stage in LDS, store coalesced 16B/lane full lines.
    #pragma unroll
    for (int t = 0; t < 8; ++t) {
        const int col  = n0 + t * 16 + l15;
        const int cloc = wn * 128 + t * 16 + l15;
        const float bias = (col < VOCAB) ? bfc[col] : 0.f;
        #pragma unroll
        for (int i = 0; i < 2; ++i)
            #pragma unroll
            for (int r = 0; r < 4; ++r) {
                const int rloc = wm * 32 + i * 16 + q * 4 + r;
                cbuf[rloc * 256 + cloc] = __float2bfloat16(acc[i][t][r] + bias);
            }
    }
    __syncthreads();
    bf16* ob = (bf16*)outp;
    for (int cidx = threadIdx.x; cidx < 64 * 32; cidx += 256) {
        const int row = cidx >> 5;
        const int c8  = (cidx & 31) * 8;
        const int gcol = bn * 256 + c8;          // VOCAB % 8 == 0: chunk all-in/out
        if (gcol < VOCAB)
            *(bf16x8*)(ob + (size_t)(bm * 64 + row) * VOCAB + gcol) =
                *(const bf16x8*)&cbuf[row * 256 + c8];
    }
}

// Runs BEFORE proj (y1 scratch is in d_out's logits region).
__global__ __launch_bounds__(256) void state_copy(
    const bf16* __restrict__ y1, const bf16* __restrict__ y2,
    void* __restrict__ outp, const void* __restrict__ det)
{
    const bool f32out = detect_fp32(det);
    const int t = blockIdx.x * blockDim.x + threadIdx.x;
    const int BH = BATCH * HIDDEN;
    const size_t ofs = (size_t)SEQ * BATCH * VOCAB;
    float v;
    if (t < BH) v = b2f(y1[(size_t)(SEQ - 1) * BH + t]);
    else        v = b2f(y2[(size_t)(SEQ - 1) * BH + (t - BH)]);
    if (f32out) ((float*)outp)[ofs + t] = v;
    else        ((bf16*)outp)[ofs + t] = __float2bfloat16(v);
}

extern "C" void kernel_launch(void* const* d_in, const int* in_sizes, int n_in,
                              void* d_out, int out_size, void* d_ws, size_t ws_size,
                              hipStream_t stream) {
    const int*  x       = (const int*)d_in[0];
    const void* Wih1raw = d_in[1];
    const void* Whh1raw = d_in[2];
    const void* bih1    = d_in[3];
    const void* bhh1    = d_in[4];
    const void* Wih2raw = d_in[5];
    const void* Whh2raw = d_in[6];
    const void* bih2    = d_in[7];
    const void* bhh2    = d_in[8];
    const void* Wfcraw  = d_in[9];
    const void* bfcraw  = d_in[10];

    // ws layout: flags (1 KB), bf16 arrays, fp32 biases (~33 MB total).
    // y1 full (S,B,H) history lives in d_out's logits region (16.8 MB scratch,
    // overwritten by proj at the end) so ws footprint does not grow.
    char* wsb = (char*)d_ws;
    int*   f1    = (int*)wsb;                                    // SEQ ints
    int*   f2    = f1 + SEQ;                                     // SEQ ints
    bf16*  y2    = (bf16*)(wsb + 1024);
    bf16*  whh1  = y2   + (size_t)SEQ * BATCH * HIDDEN;
    bf16*  wih2  = whh1 + (size_t)HIDDEN * HIDDEN;
    bf16*  whh2  = wih2 + (size_t)HIDDEN * HIDDEN;
    bf16*  wfcb  = whh2 + (size_t)HIDDEN * HIDDEN;
    float* bias1 = (float*)(wfcb + (size_t)VOCAB * HIDDEN);
    float* bias2 = bias1 + HIDDEN;
    float* bfcf  = bias2 + HIDDEN;
    bf16*  y1    = (bf16*)d_out;                                 // scratch

    // Allow >128K dynamic LDS (host-side attribute; graph-capture-safe).
    static bool lds_ok = false;
    if (!lds_ok) {
        (void)hipFuncSetAttribute((const void*)rnn_persistent,
                                  hipFuncAttributeMaxDynamicSharedMemorySize, LDS_BYTES);
        lds_ok = true;
    }

    (void)hipMemsetAsync(f1, 0, 2 * SEQ * sizeof(int), stream);

    const int HH = HIDDEN * HIDDEN, VH = VOCAB * HIDDEN;
    convert_w<<<(HH + 1023) / 1024, 256, 0, stream>>>(Whh1raw, whh1, HH, Wih1raw);
    convert_w<<<(HH + 1023) / 1024, 256, 0, stream>>>(Wih2raw, wih2, HH, Wih1raw);
    convert_w<<<(HH + 1023) / 1024, 256, 0, stream>>>(Whh2raw, whh2, HH, Wih1raw);
    convert_w<<<(VH + 1023) / 1024, 256, 0, stream>>>(Wfcraw,  wfcb, VH, Wih1raw);
    make_bias<<<(HIDDEN + 255) / 256, 256, 0, stream>>>(bih1, bhh1, bias1, HIDDEN, Wih1raw);
    make_bias<<<(HIDDEN + 255) / 256, 256, 0, stream>>>(bih2, bhh2, bias2, HIDDEN, Wih1raw);
    make_bias<<<(VOCAB + 255) / 256, 256, 0, stream>>>(bfcraw, nullptr, bfcf, VOCAB, Wih1raw);

    // 48-block decoupled recurrence (cached consumer reads, write-once y1,
    // relaxed flags, full register-staged A-operand reads).
    rnn_persistent<<<NBLK, 256, LDS_BYTES, stream>>>(x, Wih1raw, whh1, wih2, whh2,
                                                     bias1, bias2, y1, y2, f1, f2);

    // state_copy BEFORE proj: proj overwrites the y1 scratch region.
    state_copy<<<(2 * BATCH * HIDDEN) / 256, 256, 0, stream>>>(y1, y2, d_out, Wih1raw);
    proj<<<dim3(128, 20), 256, 0, stream>>>(y2, wfcb, bfcf, d_out, Wih1raw);
}